// Round 1
// 322.189 us; speedup vs baseline: 1.0388x; 1.0388x over previous
//
#include <hip/hip_runtime.h>
#include <stdint.h>

#define M_TOT 16384      // B*S = 4*4096
#define K_DIM 2048
#define N_DIM 2048
#define W_ELEMS (N_DIM * K_DIM)   // 4194304

typedef int v4i __attribute__((ext_vector_type(4)));

// ---------------- async global -> LDS, 16B per lane ----------------
__device__ __forceinline__ void async_load16(const void* gptr, void* lptr) {
    __builtin_amdgcn_global_load_lds(
        (__attribute__((address_space(1))) void*)(uintptr_t)gptr,
        (__attribute__((address_space(3))) void*)(uint32_t)(uintptr_t)lptr,
        16, 0, 0);
}

// ---------------- weight sum (for mean), double-accurate ----------------
__global__ void wsum_kernel(const float* __restrict__ w, double* __restrict__ sums) {
    int tid = blockIdx.x * 256 + threadIdx.x;
    const float4* w4 = (const float4*)w;
    double s = 0.0;
    for (int i = tid; i < W_ELEMS / 4; i += 512 * 256) {
        float4 v = w4[i];
        s += (double)v.x + (double)v.y + (double)v.z + (double)v.w;
    }
    #pragma unroll
    for (int off = 32; off; off >>= 1) s += __shfl_down(s, off);
    __shared__ double ls[4];
    if ((threadIdx.x & 63) == 0) ls[threadIdx.x >> 6] = s;
    __syncthreads();
    if (threadIdx.x == 0) atomicAdd(&sums[0], ls[0] + ls[1] + ls[2] + ls[3]);
}

// ---------------- sum |w - mean| ----------------
__global__ void wabs_kernel(const float* __restrict__ w, double* __restrict__ sums) {
    double mean = sums[0] * (1.0 / (double)W_ELEMS);
    int tid = blockIdx.x * 256 + threadIdx.x;
    const float4* w4 = (const float4*)w;
    double s = 0.0;
    for (int i = tid; i < W_ELEMS / 4; i += 512 * 256) {
        float4 v = w4[i];
        s += fabs((double)v.x - mean) + fabs((double)v.y - mean) +
             fabs((double)v.z - mean) + fabs((double)v.w - mean);
    }
    #pragma unroll
    for (int off = 32; off; off >>= 1) s += __shfl_down(s, off);
    __shared__ double ls[4];
    if ((threadIdx.x & 63) == 0) ls[threadIdx.x >> 6] = s;
    __syncthreads();
    if (threadIdx.x == 0) atomicAdd(&sums[1], ls[0] + ls[1] + ls[2] + ls[3]);
}

// ---------------- ternary weight quant -> int8 ----------------
__device__ __forceinline__ int qclamp(float v, int lo, int hi) {
    int q = (int)rintf(v);
    q = q > hi ? hi : (q < lo ? lo : q);
    return q & 255;
}

__global__ void wquant_kernel(const float* __restrict__ w, const double* __restrict__ sums,
                              int8_t* __restrict__ wq) {
    float mean  = (float)(sums[0] * (1.0 / (double)W_ELEMS));
    float scale = (float)fmax(sums[1] * (1.0 / (double)W_ELEMS), 1e-5);
    int i = blockIdx.x * 256 + threadIdx.x;      // one float4 per thread, exact cover
    float4 v = ((const float4*)w)[i];
    int p = qclamp((v.x - mean) / scale, -1, 1)
          | (qclamp((v.y - mean) / scale, -1, 1) << 8)
          | (qclamp((v.z - mean) / scale, -1, 1) << 16)
          | (qclamp((v.w - mean) / scale, -1, 1) << 24);
    ((int*)wq)[i] = p;
}

// ---------------- per-row absmax int8 quant of x (wave-per-row) ----------------
// One 64-lane wave owns one row: 8 float4 loads/lane (128 B of ILP), pure
// shfl_xor max reduce (max is order-exact in f32), no LDS, no __syncthreads.
__global__ __launch_bounds__(256) void xquant_kernel(const float* __restrict__ x,
                                                     int8_t* __restrict__ xq,
                                                     float* __restrict__ xscale) {
    const int row  = (blockIdx.x << 2) | (threadIdx.x >> 6);
    const int lane = threadIdx.x & 63;
    const float4* xr = (const float4*)(x + (size_t)row * K_DIM);
    float4 v[8];
    #pragma unroll
    for (int i = 0; i < 8; i++) v[i] = xr[lane + (i << 6)];
    float m = 0.0f;
    #pragma unroll
    for (int i = 0; i < 8; i++) {
        m = fmaxf(m, fmaxf(fmaxf(fabsf(v[i].x), fabsf(v[i].y)),
                           fmaxf(fabsf(v[i].z), fabsf(v[i].w))));
    }
    #pragma unroll
    for (int off = 32; off; off >>= 1) m = fmaxf(m, __shfl_xor(m, off));
    const float scale = fmaxf(m, 1e-5f);
    if (lane == 0) xscale[row] = scale;
    int* outp = (int*)(xq + (size_t)row * K_DIM);
    #pragma unroll
    for (int i = 0; i < 8; i++) {
        int p = qclamp(v[i].x / scale * 127.0f, -128, 127)
              | (qclamp(v[i].y / scale * 127.0f, -128, 127) << 8)
              | (qclamp(v[i].z / scale * 127.0f, -128, 127) << 16)
              | (qclamp(v[i].w / scale * 127.0f, -128, 127) << 24);
        outp[lane + (i << 6)] = p;
    }
}

// ---------------- int8 GEMM: 256x256 tile, BK=128, 8 waves, 8-phase ----------------
// Port of the verified 256^2 8-phase template (T3+T4+T5) to i8 16x16x64 MFMA.
//   LDS: per operand per buffer [2 k-half][256 rows][64 B] (16B chunks,
//        slot s = c ^ ((r>>1)&3) — same conflict-free involution as before,
//        applied on the *global source* so global_load_lds dest stays linear).
//   Phases per K-tile: P0=(mi 0-3,kh0) P1=(mi 4-7,kh0) P2=(mi 0-3,kh1) P3=(mi 4-7,kh1).
//   Staging (tile T+1) one half per phase: P0:A-k0 P1:B-k0 P2:A-k1 P3:B-k1.
//   Counted waits, never 0 in main loop:
//     P1: vmcnt(4) -> k-half1(T) landed (needed by P2/P3 reads)
//     P3: vmcnt(4) -> k-half0(T+1) landed (needed by T+1.P0/P1 reads)
//   In flight: 4-8 loads at all times. Last tile peeled with a single vmcnt(0).
//   s_setprio(1) wraps each 16-MFMA cluster (T5; pays only in 8-phase form).
__global__ __launch_bounds__(512, 2) void gemm_i8_kernel(
    const int8_t* __restrict__ xq, const int8_t* __restrict__ wq,
    const float* __restrict__ xscale, const double* __restrict__ sums,
    float* __restrict__ out)
{
    __shared__ __align__(16) int8_t lsA[2][32768];   // [buf][khalf*16384 + row*64 + slot*16]
    __shared__ __align__(16) int8_t lsB[2][32768];

    const int tid  = threadIdx.x;
    const int lane = tid & 63;
    const int wv   = tid >> 6;

    // bijective XCD swizzle: 512 wgs, 64 per XCD; each XCD owns bm in [8x,8x+8), bn fastest
    const int flat = blockIdx.x;
    const int nf   = ((flat & 7) << 6) | (flat >> 3);
    const int bm   = nf >> 3;
    const int bn   = nf & 7;

    // ---- staging addressing: thread t covers (row=t>>2, slot=t&3) within a k-half ----
    // data chunk stored at slot s of row r is c = s ^ ((r>>1)&3)
    const int sChunk = ((tid & 3) ^ ((tid >> 3) & 3)) << 4;
    const int8_t* gAb = xq + (size_t)(bm * 256 + (tid >> 2)) * K_DIM + sChunk;
    const int8_t* gBb = wq + (size_t)(bn * 256 + (tid >> 2)) * K_DIM + sChunk;
    const int sDst = tid * 16;

    #define STAGE(OP, NB, K0, KH)                                              \
        do {                                                                   \
            async_load16(g##OP##b + (K0) + (KH) * 64,                          \
                         ls##OP[NB] + (KH) * 16384 + sDst);                    \
            async_load16(g##OP##b + (K0) + (KH) * 64 + (size_t)128 * K_DIM,    \
                         ls##OP[NB] + (KH) * 16384 + 8192 + sDst);             \
        } while (0)

    #define VM4 asm volatile("s_waitcnt vmcnt(4)" ::: "memory")
    #define VM0 asm volatile("s_waitcnt vmcnt(0)" ::: "memory")

    // ---- per-wave fragment addressing ----
    const int wm  = (wv >> 2) * 128;            // 0 / 128 : wave's A half
    const int wn  = (wv & 3) * 64;              // wave's 64-col B panel
    const int fr  = lane & 15;
    const int fcl = lane >> 4;                  // 16B chunk within k-half
    int aoff[8], boff[4];
    #pragma unroll
    for (int i = 0; i < 8; i++) {
        int ra = wm + i * 16 + fr;
        aoff[i] = ra * 64 + ((fcl ^ ((ra >> 1) & 3)) << 4);
    }
    #pragma unroll
    for (int j = 0; j < 4; j++) {
        int rb = wn + j * 16 + fr;
        boff[j] = rb * 64 + ((fcl ^ ((rb >> 1) & 3)) << 4);
    }

    v4i acc[8][4] = {};
    v4i bf[4];

    #define PHASE(CB, KH, Q, LOADB, EXTRA)                                     \
        do {                                                                   \
            const int8_t* pA_ = lsA[CB] + (KH) * 16384;                        \
            const int8_t* pB_ = lsB[CB] + (KH) * 16384;                        \
            v4i af[4];                                                         \
            _Pragma("unroll")                                                  \
            for (int i_ = 0; i_ < 4; i_++)                                     \
                af[i_] = *(const v4i*)(pA_ + aoff[(Q) * 4 + i_]);              \
            if (LOADB) {                                                       \
                _Pragma("unroll")                                              \
                for (int j_ = 0; j_ < 4; j_++)                                 \
                    bf[j_] = *(const v4i*)(pB_ + boff[j_]);                    \
            }                                                                  \
            EXTRA;                                                             \
            __builtin_amdgcn_s_barrier();                                      \
            __builtin_amdgcn_s_setprio(1);                                     \
            _Pragma("unroll")                                                  \
            for (int i_ = 0; i_ < 4; i_++)                                     \
                _Pragma("unroll")                                              \
                for (int j_ = 0; j_ < 4; j_++)                                 \
                    acc[(Q) * 4 + i_][j_] =                                    \
                        __builtin_amdgcn_mfma_i32_16x16x64_i8(                 \
                            af[i_], bf[j_], acc[(Q) * 4 + i_][j_], 0, 0, 0);   \
            __builtin_amdgcn_s_setprio(0);                                     \
            __builtin_amdgcn_s_barrier();                                      \
        } while (0)

    // prologue: stage tile 0 (order: A-k0, B-k0, A-k1, B-k1), wait k-half0 only
    STAGE(A, 0, 0, 0);
    STAGE(B, 0, 0, 0);
    STAGE(A, 0, 0, 1);
    STAGE(B, 0, 0, 1);
    VM4;                                        // k-half0(0) landed; k-half1 in flight
    __builtin_amdgcn_s_barrier();

    // main loop: tiles 0..14, staging tile t+1
    for (int t = 0; t < 15; ++t) {
        const int cur = t & 1, nxt = cur ^ 1;
        const int kn = (t + 1) << 7;
        PHASE(cur, 0, 0, true,  STAGE(A, nxt, kn, 0));
        PHASE(cur, 0, 1, false, STAGE(B, nxt, kn, 0); VM4);
        PHASE(cur, 1, 0, true,  STAGE(A, nxt, kn, 1));
        PHASE(cur, 1, 1, false, STAGE(B, nxt, kn, 1); VM4);
    }
    // peeled last tile (buf 1): nothing left to stage; single drain for k-half1
    PHASE(1, 0, 0, true,  (void)0);
    PHASE(1, 0, 1, false, VM0);
    PHASE(1, 1, 0, true,  (void)0);
    PHASE(1, 1, 1, false, (void)0);

    #undef PHASE
    #undef STAGE
    #undef VM4
    #undef VM0

    // epilogue: dequant. C/D layout: col = lane&15, row = (lane>>4)*4 + reg
    float wscale = (float)fmax(sums[1] * (1.0 / (double)W_ELEMS), 1e-5);
    float f127 = wscale * (1.0f / 127.0f);
    #pragma unroll
    for (int mi = 0; mi < 8; mi++) {
        #pragma unroll
        for (int rg = 0; rg < 4; rg++) {
            int mg = bm * 256 + wm + mi * 16 + (lane >> 4) * 4 + rg;
            float fs = f127 * xscale[mg];
            float* orow = out + (size_t)mg * N_DIM + bn * 256 + wn;
            #pragma unroll
            for (int nj = 0; nj < 4; nj++)
                orow[nj * 16 + fr] = fs * (float)acc[mi][nj][rg];
        }
    }
}

extern "C" void kernel_launch(void* const* d_in, const int* in_sizes, int n_in,
                              void* d_out, int out_size, void* d_ws, size_t ws_size,
                              hipStream_t stream) {
    const float* x = (const float*)d_in[0];
    const float* w = (const float*)d_in[1];
    float* out = (float*)d_out;

    char* ws = (char*)d_ws;
    double* sums   = (double*)ws;                               // 16 B
    float*  xscale = (float*)(ws + 64);                         // 64 KB
    int8_t* xq     = (int8_t*)(ws + 64 + 65536);                // 32 MB
    int8_t* wq     = (int8_t*)(ws + 64 + 65536 + (size_t)M_TOT * K_DIM); // 4 MB

    hipMemsetAsync(sums, 0, 16, stream);
    wsum_kernel <<<512, 256, 0, stream>>>(w, sums);
    wabs_kernel <<<512, 256, 0, stream>>>(w, sums);
    wquant_kernel<<<W_ELEMS / 1024, 256, 0, stream>>>(w, sums, wq);
    xquant_kernel<<<M_TOT / 4, 256, 0, stream>>>(x, xq, xscale);
    gemm_i8_kernel<<<dim3(N_DIM / 256 * (M_TOT / 256)), 512, 0, stream>>>(xq, wq, xscale, sums, out);
}

// Round 2
// 318.077 us; speedup vs baseline: 1.0522x; 1.0129x over previous
//
#include <hip/hip_runtime.h>
#include <stdint.h>

#define M_TOT 16384      // B*S = 4*4096
#define K_DIM 2048
#define N_DIM 2048
#define W_ELEMS (N_DIM * K_DIM)   // 4194304

typedef int v4i __attribute__((ext_vector_type(4)));

// ---------------- async global -> LDS, 16B per lane ----------------
__device__ __forceinline__ void async_load16(const void* gptr, void* lptr) {
    __builtin_amdgcn_global_load_lds(
        (__attribute__((address_space(1))) void*)(uintptr_t)gptr,
        (__attribute__((address_space(3))) void*)(uint32_t)(uintptr_t)lptr,
        16, 0, 0);
}

__device__ __forceinline__ int qclamp(float v, int lo, int hi) {
    int q = (int)rintf(v);
    q = q > hi ? hi : (q < lo ? lo : q);
    return q & 255;
}

// ---------------- K1: per-block weight sum partials (no atomics, no memset) ----
__global__ __launch_bounds__(256) void wsum_kernel(const float* __restrict__ w,
                                                   double* __restrict__ spart) {
    int tid = blockIdx.x * 256 + threadIdx.x;
    const float4* w4 = (const float4*)w;
    double s = 0.0;
    #pragma unroll
    for (int it = 0; it < 8; it++) {               // 512*256*8 float4 = W_ELEMS/4 exact
        float4 v = w4[tid + it * 131072];
        s += (double)v.x + (double)v.y + (double)v.z + (double)v.w;
    }
    #pragma unroll
    for (int off = 32; off; off >>= 1) s += __shfl_down(s, off);
    __shared__ double ls[4];
    if ((threadIdx.x & 63) == 0) ls[threadIdx.x >> 6] = s;
    __syncthreads();
    if (threadIdx.x == 0) spart[blockIdx.x] = ls[0] + ls[1] + ls[2] + ls[3];
}

// ---------------- K2: per-block sum |w - mean| partials ----------------
__global__ __launch_bounds__(256) void wabs_kernel(const float* __restrict__ w,
                                                   const double* __restrict__ spart,
                                                   double* __restrict__ apart) {
    __shared__ double ls[4];
    double sm = spart[threadIdx.x] + spart[threadIdx.x + 256];
    #pragma unroll
    for (int off = 32; off; off >>= 1) sm += __shfl_down(sm, off);
    if ((threadIdx.x & 63) == 0) ls[threadIdx.x >> 6] = sm;
    __syncthreads();
    double mean = (ls[0] + ls[1] + ls[2] + ls[3]) * (1.0 / (double)W_ELEMS);
    __syncthreads();                                // ls reused below
    int tid = blockIdx.x * 256 + threadIdx.x;
    const float4* w4 = (const float4*)w;
    double s = 0.0;
    #pragma unroll
    for (int it = 0; it < 8; it++) {
        float4 v = w4[tid + it * 131072];
        s += fabs((double)v.x - mean) + fabs((double)v.y - mean) +
             fabs((double)v.z - mean) + fabs((double)v.w - mean);
    }
    #pragma unroll
    for (int off = 32; off; off >>= 1) s += __shfl_down(s, off);
    if ((threadIdx.x & 63) == 0) ls[threadIdx.x >> 6] = s;
    __syncthreads();
    if (threadIdx.x == 0) apart[blockIdx.x] = ls[0] + ls[1] + ls[2] + ls[3];
}

// ---------------- K3: fused x-quant (blocks 0..4095) + w-quant (4096..8191) ----
__global__ __launch_bounds__(256) void quant_kernel(
    const float* __restrict__ x, const float* __restrict__ w,
    const double* __restrict__ spart, const double* __restrict__ apart,
    int8_t* __restrict__ xq, int8_t* __restrict__ wq,
    float* __restrict__ xscale, float* __restrict__ wsf)
{
    const int t = threadIdx.x;
    if (blockIdx.x < 4096) {
        // ---- per-row absmax int8 quant of x: one wave per row ----
        const int row  = (blockIdx.x << 2) | (t >> 6);
        const int lane = t & 63;
        const float4* xr = (const float4*)(x + (size_t)row * K_DIM);
        float4 v[8];
        #pragma unroll
        for (int i = 0; i < 8; i++) v[i] = xr[lane + (i << 6)];
        float m = 0.0f;
        #pragma unroll
        for (int i = 0; i < 8; i++)
            m = fmaxf(m, fmaxf(fmaxf(fabsf(v[i].x), fabsf(v[i].y)),
                               fmaxf(fabsf(v[i].z), fabsf(v[i].w))));
        #pragma unroll
        for (int off = 32; off; off >>= 1) m = fmaxf(m, __shfl_xor(m, off));
        const float scale = fmaxf(m, 1e-5f);
        if (lane == 0) xscale[row] = scale;
        int* outp = (int*)(xq + (size_t)row * K_DIM);
        #pragma unroll
        for (int i = 0; i < 8; i++) {
            int p = qclamp(v[i].x / scale * 127.0f, -128, 127)
                  | (qclamp(v[i].y / scale * 127.0f, -128, 127) << 8)
                  | (qclamp(v[i].z / scale * 127.0f, -128, 127) << 16)
                  | (qclamp(v[i].w / scale * 127.0f, -128, 127) << 24);
            outp[lane + (i << 6)] = p;
        }
    } else {
        // ---- ternary w-quant; mean/scale re-reduced from 512+512 partials ----
        __shared__ double ls0[4], ls1[4];
        double s0 = spart[t] + spart[t + 256];
        double s1 = apart[t] + apart[t + 256];
        #pragma unroll
        for (int off = 32; off; off >>= 1) {
            s0 += __shfl_down(s0, off);
            s1 += __shfl_down(s1, off);
        }
        if ((t & 63) == 0) { ls0[t >> 6] = s0; ls1[t >> 6] = s1; }
        __syncthreads();
        float mean  = (float)((ls0[0] + ls0[1] + ls0[2] + ls0[3]) * (1.0 / (double)W_ELEMS));
        float scale = (float)fmax((ls1[0] + ls1[1] + ls1[2] + ls1[3]) * (1.0 / (double)W_ELEMS), 1e-5);
        int i = (blockIdx.x - 4096) * 256 + t;      // one float4 per thread, exact cover
        float4 v = ((const float4*)w)[i];
        int p = qclamp((v.x - mean) / scale, -1, 1)
              | (qclamp((v.y - mean) / scale, -1, 1) << 8)
              | (qclamp((v.z - mean) / scale, -1, 1) << 16)
              | (qclamp((v.w - mean) / scale, -1, 1) << 24);
        ((int*)wq)[i] = p;
        if (i == 0) wsf[0] = scale * (1.0f / 127.0f);   // dequant factor for gemm
    }
}

// ---------------- int8 GEMM: 128x128 tile, BK=128, 4 waves, 64 KiB LDS ----------
// 2 blocks/CU (the round-1 256^2 version was 128 KiB -> 1 block/CU and barrier-
// lockstepped all 8 waves: LDS window and MFMA window fully serialized, MfmaUtil
// 32%). Two independent barrier domains per CU let one block's MFMA phase cover
// the other's LDS/barrier window.
//   LDS per op per buf: [2 khalf][128 rows][64 B], chunk-slot swizzle
//   s = c ^ ((r>>1)&3) applied on the global source (proven 0-conflict).
//   2 phases/tile (one per khalf, 16 MFMA each). Stage one khalf of A+B per
//   phase (4 loads). VM4 once per phase: in-flight 4-8 loads, never drained
//   to 0 in the main loop; single VM0 at the peeled tail.
__global__ __launch_bounds__(256, 2) void gemm_i8_kernel(
    const int8_t* __restrict__ xq, const int8_t* __restrict__ wq,
    const float* __restrict__ xscale, const float* __restrict__ wsf,
    float* __restrict__ out)
{
    __shared__ __align__(16) int8_t lsA[2][16384];   // [buf][kh*8192 + row*64 + slot*16]
    __shared__ __align__(16) int8_t lsB[2][16384];

    const int tid  = threadIdx.x;
    const int lane = tid & 63;
    const int wv   = tid >> 6;

    // bijective XCD swizzle: 2048 wgs, 256/XCD; XCD x owns bm in [16x,16x+16), bn fastest
    const int flat = blockIdx.x;
    const int nf   = ((flat & 7) << 8) | (flat >> 3);
    const int bm   = nf >> 4;                        // 0..127
    const int bn   = nf & 15;                        // 0..15

    // staging: thread t covers (row=t>>2 in 0..63, slot=t&3); chunk c = s ^ ((r>>1)&3)
    const int sChunk = ((tid & 3) ^ ((tid >> 3) & 3)) << 4;
    const int8_t* gAb = xq + (size_t)(bm * 128 + (tid >> 2)) * K_DIM + sChunk;
    const int8_t* gBb = wq + (size_t)(bn * 128 + (tid >> 2)) * K_DIM + sChunk;
    const int sDst = tid * 16;

    // one khalf of one operand = 128 rows x 64 B = 8 KB = 2 loads/thread
    // row r+64 has the same xor (((r+64)>>1)&3 == ((r>>1)&3))
    #define STAGE(OP, NB, K0, KH)                                              \
        do {                                                                   \
            async_load16(g##OP##b + (K0) + (KH) * 64,                          \
                         ls##OP[NB] + (KH) * 8192 + sDst);                     \
            async_load16(g##OP##b + (K0) + (KH) * 64 + (size_t)64 * K_DIM,     \
                         ls##OP[NB] + (KH) * 8192 + 4096 + sDst);              \
        } while (0)

    #define VM4 asm volatile("s_waitcnt vmcnt(4)" ::: "memory")
    #define VM0 asm volatile("s_waitcnt vmcnt(0)" ::: "memory")

    // per-wave fragments: wave = 64x64 output (4x4 of 16x16)
    const int wm  = (wv >> 1) * 64;
    const int wn  = (wv & 1) * 64;
    const int fr  = lane & 15;
    const int fcl = lane >> 4;                       // 16B chunk within khalf
    int aoff[4], boff[4];
    #pragma unroll
    for (int i = 0; i < 4; i++) {
        int ra = wm + i * 16 + fr;
        aoff[i] = ra * 64 + ((fcl ^ ((ra >> 1) & 3)) << 4);
        int rb = wn + i * 16 + fr;
        boff[i] = rb * 64 + ((fcl ^ ((rb >> 1) & 3)) << 4);
    }

    v4i acc[4][4] = {};

    #define PHASE(CB, KH, EXTRA)                                               \
        do {                                                                   \
            const int8_t* pA_ = lsA[CB] + (KH) * 8192;                         \
            const int8_t* pB_ = lsB[CB] + (KH) * 8192;                         \
            v4i af[4], bf[4];                                                  \
            _Pragma("unroll")                                                  \
            for (int i_ = 0; i_ < 4; i_++) {                                   \
                af[i_] = *(const v4i*)(pA_ + aoff[i_]);                        \
                bf[i_] = *(const v4i*)(pB_ + boff[i_]);                        \
            }                                                                  \
            EXTRA;                                                             \
            __builtin_amdgcn_s_barrier();                                      \
            __builtin_amdgcn_s_setprio(1);                                     \
            _Pragma("unroll")                                                  \
            for (int i_ = 0; i_ < 4; i_++)                                     \
                _Pragma("unroll")                                              \
                for (int j_ = 0; j_ < 4; j_++)                                 \
                    acc[i_][j_] = __builtin_amdgcn_mfma_i32_16x16x64_i8(       \
                        af[i_], bf[j_], acc[i_][j_], 0, 0, 0);                 \
            __builtin_amdgcn_s_setprio(0);                                     \
            __builtin_amdgcn_s_barrier();                                      \
        } while (0)

    // prologue: stage tile 0 (kh0 first), wait kh0 only; kh1 stays in flight
    STAGE(A, 0, 0, 0);
    STAGE(B, 0, 0, 0);
    STAGE(A, 0, 0, 1);
    STAGE(B, 0, 0, 1);
    VM4;
    __builtin_amdgcn_s_barrier();

    // main loop: tiles 0..14, staging tile t+1 one khalf per phase.
    //   end of PHASE(kh0): VM4 -> kh1(t) landed (read next phase)
    //   end of PHASE(kh1): VM4 -> kh0(t+1) landed (read next tile)
    #pragma unroll 2
    for (int t = 0; t < 15; ++t) {
        const int cur = t & 1, nxt = cur ^ 1;
        const int kn = (t + 1) << 7;
        PHASE(cur, 0, STAGE(A, nxt, kn, 0); STAGE(B, nxt, kn, 0); VM4);
        PHASE(cur, 1, STAGE(A, nxt, kn, 1); STAGE(B, nxt, kn, 1); VM4);
    }
    // peeled last tile (buf 1): kh0 already landed; drain kh1 BEFORE its reads
    PHASE(1, 0, (void)0);
    VM0;
    __builtin_amdgcn_s_barrier();
    PHASE(1, 1, (void)0);

    #undef PHASE
    #undef STAGE
    #undef VM4
    #undef VM0

    // epilogue: dequant. C/D layout: col = lane&15, row = (lane>>4)*4 + reg
    const float f127 = wsf[0];
    #pragma unroll
    for (int mi = 0; mi < 4; mi++) {
        #pragma unroll
        for (int rg = 0; rg < 4; rg++) {
            int mg = bm * 128 + wm + mi * 16 + (lane >> 4) * 4 + rg;
            float fs = f127 * xscale[mg];
            float* orow = out + (size_t)mg * N_DIM + bn * 128 + wn;
            #pragma unroll
            for (int nj = 0; nj < 4; nj++)
                orow[nj * 16 + fr] = fs * (float)acc[mi][nj][rg];
        }
    }
}

extern "C" void kernel_launch(void* const* d_in, const int* in_sizes, int n_in,
                              void* d_out, int out_size, void* d_ws, size_t ws_size,
                              hipStream_t stream) {
    const float* x = (const float*)d_in[0];
    const float* w = (const float*)d_in[1];
    float* out = (float*)d_out;

    char* ws = (char*)d_ws;
    double* spart  = (double*)ws;                    // 4 KB (512 doubles)
    double* apart  = (double*)(ws + 4096);           // 4 KB
    float*  wsf    = (float*)(ws + 8192);            // 4 B
    float*  xscale = (float*)(ws + 12288);           // 64 KB
    int8_t* xq     = (int8_t*)(ws + 12288 + 65536);  // 32 MB
    int8_t* wq     = xq + (size_t)M_TOT * K_DIM;     // 4 MB

    wsum_kernel <<<512, 256, 0, stream>>>(w, spart);
    wabs_kernel <<<512, 256, 0, stream>>>(w, spart, apart);
    quant_kernel<<<8192, 256, 0, stream>>>(x, w, spart, apart, xq, wq, xscale, wsf);
    gemm_i8_kernel<<<2048, 256, 0, stream>>>(xq, wq, xscale, wsf, out);
}

// Round 4
// 312.304 us; speedup vs baseline: 1.0717x; 1.0185x over previous
//
#include <hip/hip_runtime.h>
#include <stdint.h>

#define M_TOT 16384      // B*S = 4*4096
#define K_DIM 2048
#define N_DIM 2048
#define W_ELEMS (N_DIM * K_DIM)   // 4194304

typedef int v4i  __attribute__((ext_vector_type(4)));
typedef int v16i __attribute__((ext_vector_type(16)));

// ---------------- async global -> LDS, 16B per lane ----------------
__device__ __forceinline__ void async_load16(const void* gptr, void* lptr) {
    __builtin_amdgcn_global_load_lds(
        (__attribute__((address_space(1))) void*)(uintptr_t)gptr,
        (__attribute__((address_space(3))) void*)(uint32_t)(uintptr_t)lptr,
        16, 0, 0);
}

__device__ __forceinline__ int qclamp(float v, int lo, int hi) {
    int q = (int)rintf(v);
    q = q > hi ? hi : (q < lo ? lo : q);
    return q & 255;
}

// ---------------- K1: per-block weight sum partials (no atomics, no memset) ----
__global__ __launch_bounds__(256) void wsum_kernel(const float* __restrict__ w,
                                                   double* __restrict__ spart) {
    int tid = blockIdx.x * 256 + threadIdx.x;
    const float4* w4 = (const float4*)w;
    double s = 0.0;
    #pragma unroll
    for (int it = 0; it < 8; it++) {               // 512*256*8 float4 = W_ELEMS/4 exact
        float4 v = w4[tid + it * 131072];
        s += (double)v.x + (double)v.y + (double)v.z + (double)v.w;
    }
    #pragma unroll
    for (int off = 32; off; off >>= 1) s += __shfl_down(s, off);
    __shared__ double ls[4];
    if ((threadIdx.x & 63) == 0) ls[threadIdx.x >> 6] = s;
    __syncthreads();
    if (threadIdx.x == 0) spart[blockIdx.x] = ls[0] + ls[1] + ls[2] + ls[3];
}

// ---------------- K2: per-block sum |w - mean| partials ----------------
__global__ __launch_bounds__(256) void wabs_kernel(const float* __restrict__ w,
                                                   const double* __restrict__ spart,
                                                   double* __restrict__ apart) {
    __shared__ double ls[4];
    double sm = spart[threadIdx.x] + spart[threadIdx.x + 256];
    #pragma unroll
    for (int off = 32; off; off >>= 1) sm += __shfl_down(sm, off);
    if ((threadIdx.x & 63) == 0) ls[threadIdx.x >> 6] = sm;
    __syncthreads();
    double mean = (ls[0] + ls[1] + ls[2] + ls[3]) * (1.0 / (double)W_ELEMS);
    __syncthreads();                                // ls reused below
    int tid = blockIdx.x * 256 + threadIdx.x;
    const float4* w4 = (const float4*)w;
    double s = 0.0;
    #pragma unroll
    for (int it = 0; it < 8; it++) {
        float4 v = w4[tid + it * 131072];
        s += fabs((double)v.x - mean) + fabs((double)v.y - mean) +
             fabs((double)v.z - mean) + fabs((double)v.w - mean);
    }
    #pragma unroll
    for (int off = 32; off; off >>= 1) s += __shfl_down(s, off);
    if ((threadIdx.x & 63) == 0) ls[threadIdx.x >> 6] = s;
    __syncthreads();
    if (threadIdx.x == 0) apart[blockIdx.x] = ls[0] + ls[1] + ls[2] + ls[3];
}

// ---------------- K3: fused x-quant (blocks 0..4095) + w-quant (4096..8191) ----
__global__ __launch_bounds__(256) void quant_kernel(
    const float* __restrict__ x, const float* __restrict__ w,
    const double* __restrict__ spart, const double* __restrict__ apart,
    int8_t* __restrict__ xq, int8_t* __restrict__ wq,
    float* __restrict__ xscale, float* __restrict__ wsf)
{
    const int t = threadIdx.x;
    if (blockIdx.x < 4096) {
        // ---- per-row absmax int8 quant of x: one wave per row ----
        const int row  = (blockIdx.x << 2) | (t >> 6);
        const int lane = t & 63;
        const float4* xr = (const float4*)(x + (size_t)row * K_DIM);
        float4 v[8];
        #pragma unroll
        for (int i = 0; i < 8; i++) v[i] = xr[lane + (i << 6)];
        float m = 0.0f;
        #pragma unroll
        for (int i = 0; i < 8; i++)
            m = fmaxf(m, fmaxf(fmaxf(fabsf(v[i].x), fabsf(v[i].y)),
                               fmaxf(fabsf(v[i].z), fabsf(v[i].w))));
        #pragma unroll
        for (int off = 32; off; off >>= 1) m = fmaxf(m, __shfl_xor(m, off));
        const float scale = fmaxf(m, 1e-5f);
        if (lane == 0) xscale[row] = scale;
        int* outp = (int*)(xq + (size_t)row * K_DIM);
        #pragma unroll
        for (int i = 0; i < 8; i++) {
            int p = qclamp(v[i].x / scale * 127.0f, -128, 127)
                  | (qclamp(v[i].y / scale * 127.0f, -128, 127) << 8)
                  | (qclamp(v[i].z / scale * 127.0f, -128, 127) << 16)
                  | (qclamp(v[i].w / scale * 127.0f, -128, 127) << 24);
            outp[lane + (i << 6)] = p;
        }
    } else {
        // ---- ternary w-quant; mean/scale re-reduced from 512+512 partials ----
        __shared__ double ls0[4], ls1[4];
        double s0 = spart[t] + spart[t + 256];
        double s1 = apart[t] + apart[t + 256];
        #pragma unroll
        for (int off = 32; off; off >>= 1) {
            s0 += __shfl_down(s0, off);
            s1 += __shfl_down(s1, off);
        }
        if ((t & 63) == 0) { ls0[t >> 6] = s0; ls1[t >> 6] = s1; }
        __syncthreads();
        float mean  = (float)((ls0[0] + ls0[1] + ls0[2] + ls0[3]) * (1.0 / (double)W_ELEMS));
        float scale = (float)fmax((ls1[0] + ls1[1] + ls1[2] + ls1[3]) * (1.0 / (double)W_ELEMS), 1e-5);
        int i = (blockIdx.x - 4096) * 256 + t;      // one float4 per thread, exact cover
        float4 v = ((const float4*)w)[i];
        int p = qclamp((v.x - mean) / scale, -1, 1)
              | (qclamp((v.y - mean) / scale, -1, 1) << 8)
              | (qclamp((v.z - mean) / scale, -1, 1) << 16)
              | (qclamp((v.w - mean) / scale, -1, 1) << 24);
        ((int*)wq)[i] = p;
        if (i == 0) wsf[0] = scale * (1.0f / 127.0f);   // dequant factor for gemm
    }
}

// ---------------- int8 GEMM: 256x256 tile, BK=128, 8 waves, ONE barrier/K-tile ----
// Round-1/2 post-mortem: both 8-phase and 2-phase structures pay ~570 cyc of
// barrier/wait overhead per ~330-650 cyc of MFMA -> MfmaUtil stuck at 30%.
// Fix: amortize. One phase = one full BK=128 K-tile = 32 x mfma_i32_32x32x32_i8
// per wave (~2340 cyc/SIMD at 2 waves/SIMD) against ONE vmcnt(0)+lgkm(0)+barrier.
//   wave tile 128x64 (mi 0..3 of 32 rows, nj 0..1 of 32 cols), 8 waves (2Mx4N).
//   LDS: [2 buf][256 rows][128 B] per operand = 128 KiB total, 1 block/CU.
//   Swizzle: row's 8 16B-chunks stored at slot s = c ^ (row&7) (bank-uniform:
//   8 accesses/bank = b128 floor). Applied on the global SOURCE address so the
//   global_load_lds destination stays linear (both-sides-or-neither rule).
//   Phase: issue 8 gload_lds (tile t+1 -> buf^1) FIRST (full-phase latency
//   cover ~2300 cyc >> 900 cyc HBM); 24 ds_read_b128 + 32 MFMA (compiler
//   inserts fine-grained lgkmcnt); vmcnt(0) is a non-stall drain at phase end;
//   single barrier publishes loads + retires reads for the buffer swap.
__global__ __launch_bounds__(512, 2) void gemm_i8_kernel(
    const int8_t* __restrict__ xq, const int8_t* __restrict__ wq,
    const float* __restrict__ xscale, const float* __restrict__ wsf,
    float* __restrict__ out)
{
    __shared__ __align__(16) int8_t lsA[2][32768];
    __shared__ __align__(16) int8_t lsB[2][32768];

    const int tid  = threadIdx.x;
    const int lane = tid & 63;
    const int wv   = tid >> 6;

    // bijective XCD swizzle: 512 wgs, 64/XCD; XCD x owns bm in [8x,8x+8), bn fastest
    const int flat = blockIdx.x;
    const int nf   = ((flat & 7) << 6) | (flat >> 3);
    const int bm   = nf >> 3;                        // 0..63
    const int bn   = nf & 7;                         // 0..7

    // staging: thread t covers (row = t>>3 in 0..63, slot = t&7); chunk c = s ^ (row&7)
    const int sChunk = (((tid & 7) ^ ((tid >> 3) & 7)) << 4);
    const int8_t* gAb = xq + (size_t)(bm * 256 + (tid >> 3)) * K_DIM + sChunk;
    const int8_t* gBb = wq + (size_t)(bn * 256 + (tid >> 3)) * K_DIM + sChunk;
    const int sDst = tid * 16;

    // one K-tile of one operand = 256 rows x 128 B = 32 KB = 4 gloads/thread
    // (g adds 64 rows: row&7 unchanged, so the chunk xor is per-thread constant)
    #define STAGE(NB, K0)                                                      \
        do {                                                                   \
            _Pragma("unroll")                                                  \
            for (int g_ = 0; g_ < 4; g_++)                                     \
                async_load16(gAb + (size_t)g_ * 64 * K_DIM + (K0),             \
                             lsA[NB] + g_ * 8192 + sDst);                      \
            _Pragma("unroll")                                                  \
            for (int g_ = 0; g_ < 4; g_++)                                     \
                async_load16(gBb + (size_t)g_ * 64 * K_DIM + (K0),             \
                             lsB[NB] + g_ * 8192 + sDst);                      \
        } while (0)

    // per-wave fragment addressing (32x32x32: lane -> row lane&31, k-chunk lane>>5)
    const int wm  = (wv >> 2) << 7;                  // 0 / 128
    const int wn  = (wv & 3) << 6;                   // 0 / 64 / 128 / 192
    const int l31 = lane & 31;
    const int hi  = lane >> 5;
    const int lx  = lane & 7;                        // = row&7 for all our rows

    int rA[4], rB[2], cs[4];
    #pragma unroll
    for (int mi = 0; mi < 4; mi++) rA[mi] = (wm + mi * 32 + l31) << 7;
    #pragma unroll
    for (int nj = 0; nj < 2; nj++) rB[nj] = (wn + nj * 32 + l31) << 7;
    #pragma unroll
    for (int ks = 0; ks < 4; ks++) cs[ks] = ((ks * 2 + hi) ^ lx) << 4;

    v16i acc[4][2] = {};

    // prologue: stage tile 0 -> buf0
    STAGE(0, 0);
    asm volatile("s_waitcnt vmcnt(0)" ::: "memory");
    __builtin_amdgcn_s_barrier();

    for (int t = 0; t < 16; ++t) {
        const int cur = t & 1;
        const int8_t* pA = lsA[cur];
        const int8_t* pB = lsB[cur];
        if (t < 15) STAGE(cur ^ 1, (t + 1) << 7);
        __builtin_amdgcn_s_setprio(1);
        #pragma unroll
        for (int ks = 0; ks < 4; ks++) {
            v4i af[4], bf[2];
            #pragma unroll
            for (int mi = 0; mi < 4; mi++)
                af[mi] = *(const v4i*)(pA + rA[mi] + cs[ks]);
            #pragma unroll
            for (int nj = 0; nj < 2; nj++)
                bf[nj] = *(const v4i*)(pB + rB[nj] + cs[ks]);
            #pragma unroll
            for (int mi = 0; mi < 4; mi++)
                #pragma unroll
                for (int nj = 0; nj < 2; nj++)
                    acc[mi][nj] = __builtin_amdgcn_mfma_i32_32x32x32_i8(
                        af[mi], bf[nj], acc[mi][nj], 0, 0, 0);
        }
        __builtin_amdgcn_s_setprio(0);
        asm volatile("s_waitcnt vmcnt(0) lgkmcnt(0)" ::: "memory");
        __builtin_amdgcn_s_barrier();
    }
    #undef STAGE

    // epilogue: dequant. 32x32 C/D: col = lane&31, row = (reg&3) + 8*(reg>>2) + 4*(lane>>5)
    const float f127 = wsf[0];
    #pragma unroll
    for (int mi = 0; mi < 4; mi++) {
        #pragma unroll
        for (int r = 0; r < 16; r++) {
            const int rowl = (r & 3) + ((r >> 2) << 3) + (hi << 2);
            const int mg = bm * 256 + wm + mi * 32 + rowl;
            const float fs = f127 * xscale[mg];
            float* orow = out + (size_t)mg * N_DIM + bn * 256 + wn + l31;
            #pragma unroll
            for (int nj = 0; nj < 2; nj++)
                orow[nj * 32] = fs * (float)acc[mi][nj][r];
        }
    }
}

extern "C" void kernel_launch(void* const* d_in, const int* in_sizes, int n_in,
                              void* d_out, int out_size, void* d_ws, size_t ws_size,
                              hipStream_t stream) {
    const float* x = (const float*)d_in[0];
    const float* w = (const float*)d_in[1];
    float* out = (float*)d_out;

    char* ws = (char*)d_ws;
    double* spart  = (double*)ws;                    // 4 KB (512 doubles)
    double* apart  = (double*)(ws + 4096);           // 4 KB
    float*  wsf    = (float*)(ws + 8192);            // 4 B
    float*  xscale = (float*)(ws + 12288);           // 64 KB
    int8_t* xq     = (int8_t*)(ws + 12288 + 65536);  // 32 MB
    int8_t* wq     = xq + (size_t)M_TOT * K_DIM;     // 4 MB

    wsum_kernel <<<512, 256, 0, stream>>>(w, spart);
    wabs_kernel <<<512, 256, 0, stream>>>(w, spart, apart);
    quant_kernel<<<8192, 256, 0, stream>>>(x, w, spart, apart, xq, wq, xscale, wsf);
    gemm_i8_kernel<<<512, 512, 0, stream>>>(xq, wq, xscale, wsf, out);
}